// Round 9
// baseline (598.261 us; speedup 1.0000x reference)
//
#include <hip/hip_runtime.h>
#include <hip/hip_bf16.h>
#include <stdint.h>

#define D 256

typedef __attribute__((ext_vector_type(8))) short bf16x8;
typedef __attribute__((ext_vector_type(4))) float f32x4;
typedef __attribute__((ext_vector_type(4))) unsigned int u32x4;

#define GLOBAL_AS __attribute__((address_space(1)))
#define LDS_AS __attribute__((address_space(3)))

__device__ __forceinline__ unsigned short f2bf(float f) {
  union { float f; unsigned int u; } c; c.f = f;
  unsigned int r = (c.u + 0x7fffu + ((c.u >> 16) & 1u)) >> 16;
  return (unsigned short)r;
}
__device__ __forceinline__ float bf2f(unsigned short h) {
  union { unsigned int u; float f; } c; c.u = ((unsigned int)h) << 16;
  return c.f;
}

// ---------------- prep: x fp32 -> bf16 ----------------
__global__ void convert_x_kernel(const float* __restrict__ x,
                                 unsigned short* __restrict__ xb, int n4) {
  int i = blockIdx.x * blockDim.x + threadIdx.x;
  if (i >= n4) return;
  float4 v = reinterpret_cast<const float4*>(x)[i];
  ushort4 o;
  o.x = f2bf(v.x); o.y = f2bf(v.y); o.z = f2bf(v.z); o.w = f2bf(v.w);
  reinterpret_cast<ushort4*>(xb)[i] = o;
}

// ---------------- prep: Wt[r][h][d] = W_r[d][h] (bf16), r==R -> W_self ----------------
__global__ void transpose_w_kernel(const float* __restrict__ Wrel,
                                   const float* __restrict__ Wself,
                                   unsigned short* __restrict__ Wt, int R) {
  __shared__ unsigned short tile[64][65];
  int r = blockIdx.z;
  const float* src = (r == R) ? Wself : (Wrel + (size_t)r * D * D);
  int d0 = blockIdx.x * 64, h0 = blockIdx.y * 64;
  for (int i = threadIdx.x; i < 64 * 64; i += blockDim.x) {
    int row = i >> 6, col = i & 63;  // row: d, col: h
    tile[row][col] = f2bf(src[(size_t)(d0 + row) * D + h0 + col]);
  }
  __syncthreads();
  for (int i = threadIdx.x; i < 64 * 64; i += blockDim.x) {
    int row = i >> 6, col = i & 63;  // row: h, col: d
    Wt[(size_t)r * D * D + (size_t)(h0 + row) * D + d0 + col] = tile[col][row];
  }
}

// ---------------- MFMA GEMM: 256x128 tile, 8 waves, panel-swizzled 1-D grid ----------------
// Blocks with ni < nxw compute xw tiles (bf16, LDS-staged epilogue in 2 halves).
// Blocks with ni >= nxw compute the fused self-transform: out = x @ W_self^T + bias (fp32).
// XB=1: A bf16 via global_load_lds. XB=0: A fp32 reg-staged + cvt.
template <int XB>
__global__ __launch_bounds__(512) void gemm_kernel(
    const unsigned short* __restrict__ Abf,
    const float* __restrict__ Af,
    const unsigned short* __restrict__ Bt,     // batch relation weights^T (nxw*128 rows)
    const unsigned short* __restrict__ Bself,  // W_self^T (256 rows)
    unsigned short* __restrict__ Cbf,          // xw output
    float* __restrict__ Cf,                    // self output (fp32)
    const float* __restrict__ bias,
    int M, int ldc, int ntiles, int nxw) {
  __shared__ unsigned short smem[256 * 64 + 128 * 64];  // As 32KB + Bs 16KB
  unsigned short* As = smem;            // [256][64]
  unsigned short* Bs = smem + 256 * 64; // [128][64]

  const int tid = threadIdx.x;
  const int lane = tid & 63;
  const int wid = tid >> 6;   // 0..7
  const int wm = wid >> 1;    // 0..3 (64-row slice)
  const int wn = wid & 1;     // 0..1 (64-col slice)

  // panel-swizzle decode (PANEL=8 m-tiles, m fastest -> XCD L2 A-reuse)
  const int MBt = (M + 255) >> 8;
  const int PANEL = 8;
  const int per_panel = PANEL * ntiles;
  const int panel = blockIdx.x / per_panel;
  const int rem = blockIdx.x - panel * per_panel;
  const int pm0 = panel * PANEL;
  const int ph = min(PANEL, MBt - pm0);
  const int mi = pm0 + rem % ph;
  const int ni = rem / ph;
  const int m0 = mi * 256;

  const bool self = (ni >= nxw);
  const int n0 = self ? 0 : ni * 128;
  const int scol0 = self ? (ni - nxw) * 128 : 0;
  const unsigned short* Bsrc = self ? (Bself + (size_t)scol0 * 256)
                                    : (Bt + (size_t)n0 * 256);

  f32x4 acc[4][4] = {};

  for (int k0 = 0; k0 < 256; k0 += 64) {
    __syncthreads();  // previous iter's LDS reads done
    // B tile: 128x64 = 16 chunks of 1KB (2 per wave)
    for (int i = 0; i < 2; ++i) {
      int chunk = i * 8 + wid;              // 0..15
      int row = chunk * 8 + (lane >> 3);    // 0..127
      int col = (lane & 7) * 8;
      const unsigned short* gb = Bsrc + (size_t)row * 256 + k0 + col;
      __builtin_amdgcn_global_load_lds((GLOBAL_AS void*)(void*)gb,
                                       (LDS_AS void*)(Bs + chunk * 512), 16, 0, 0);
    }
    // A tile: 256x64 = 32 chunks (4 per wave)
    if (XB) {
      for (int i = 0; i < 4; ++i) {
        int chunk = i * 8 + wid;            // 0..31
        int row = chunk * 8 + (lane >> 3);  // 0..255
        int col = (lane & 7) * 8;
        int ar = m0 + row; if (ar > M - 1) ar = M - 1;
        const unsigned short* ga = Abf + (size_t)ar * 256 + k0 + col;
        __builtin_amdgcn_global_load_lds((GLOBAL_AS void*)(void*)ga,
                                         (LDS_AS void*)(As + chunk * 512), 16, 0, 0);
      }
    } else {
      for (int i = 0; i < 4; ++i) {
        int idx = i * 512 + tid;   // 0..2047
        int row = idx >> 3;        // 0..255
        int c8 = idx & 7;          // 8-col group
        int ar = m0 + row; if (ar > M - 1) ar = M - 1;
        const float* src = Af + (size_t)ar * 256 + k0 + c8 * 8;
        float4 v0 = *reinterpret_cast<const float4*>(src);
        float4 v1 = *reinterpret_cast<const float4*>(src + 4);
        ushort4 o0, o1;
        o0.x = f2bf(v0.x); o0.y = f2bf(v0.y); o0.z = f2bf(v0.z); o0.w = f2bf(v0.w);
        o1.x = f2bf(v1.x); o1.y = f2bf(v1.y); o1.z = f2bf(v1.z); o1.w = f2bf(v1.w);
        *reinterpret_cast<ushort4*>(&As[row * 64 + c8 * 8]) = o0;
        *reinterpret_cast<ushort4*>(&As[row * 64 + c8 * 8 + 4]) = o1;
      }
    }
    __syncthreads();  // staging complete
    for (int kk = 0; kk < 2; ++kk) {
      bf16x8 af[4], bfr[4];
      int kof = kk * 32 + (lane >> 4) * 8;
      for (int mi2 = 0; mi2 < 4; ++mi2)
        af[mi2] = *(const bf16x8*)&As[(wm * 64 + mi2 * 16 + (lane & 15)) * 64 + kof];
      for (int ni2 = 0; ni2 < 4; ++ni2)
        bfr[ni2] = *(const bf16x8*)&Bs[(wn * 64 + ni2 * 16 + (lane & 15)) * 64 + kof];
      for (int mi2 = 0; mi2 < 4; ++mi2)
        for (int ni2 = 0; ni2 < 4; ++ni2)
          acc[mi2][ni2] = __builtin_amdgcn_mfma_f32_16x16x32_bf16(
              af[mi2], bfr[ni2], acc[mi2][ni2], 0, 0, 0);
    }
  }

  if (self) {
    // fused self-transform epilogue: fp32 + bias, direct stores
    for (int mi2 = 0; mi2 < 4; ++mi2)
      for (int ni2 = 0; ni2 < 4; ++ni2) {
        int col = scol0 + wn * 64 + ni2 * 16 + (lane & 15);
        int rbase = m0 + wm * 64 + mi2 * 16 + (lane >> 4) * 4;
        float b = bias[col];
        for (int j = 0; j < 4; ++j) {
          int row = rbase + j;
          if (row < M) Cf[(size_t)row * 256 + col] = acc[mi2][ni2][j] + b;
        }
      }
  } else {
    // bf16 epilogue, staged through LDS in two 128-row halves
    for (int h = 0; h < 2; ++h) {
      __syncthreads();  // previous use of smem done
      for (int u = 0; u < 2; ++u) {
        int mi2 = h * 2 + u;
        for (int ni2 = 0; ni2 < 4; ++ni2) {
          int col = wn * 64 + ni2 * 16 + (lane & 15);
          int lr0 = wm * 32 + u * 16 + (lane >> 4) * 4;
          for (int j = 0; j < 4; ++j)
            smem[(lr0 + j) * 128 + col] = f2bf(acc[mi2][ni2][j]);
        }
      }
      __syncthreads();
      for (int i = 0; i < 4; ++i) {
        int c = i * 512 + tid;      // 0..2047 chunks of 16B
        int row = c >> 4;           // 0..127 (local)
        int cole = (c & 15) * 8;
        int grow = m0 + (row >> 5) * 64 + h * 32 + (row & 31);
        if (grow < M)
          *(u32x4*)&Cbf[(size_t)grow * ldc + n0 + cole] =
              *(const u32x4*)&smem[row * 128 + cole];
      }
    }
  }
}

// ================= per-(batch,dst) CSR build =================
__global__ void hist_kernel(const int* __restrict__ ei, const int* __restrict__ et,
                            int* __restrict__ counts, int E, int M, int R, int RB) {
  for (int i = blockIdx.x * blockDim.x + threadIdx.x; i < E;
       i += gridDim.x * blockDim.x) {
    int dst = min(max(ei[E + i], 0), M - 1);
    int rel = min(max(et[i], 0), R - 1);
    int b = rel / RB;
    atomicAdd(&counts[b * M + dst], 1);
  }
}

__global__ void scan1_kernel(const int* __restrict__ counts, int* __restrict__ bsum,
                             int NBINS) {
  __shared__ int red[256];
  int i = blockIdx.x * 256 + threadIdx.x;
  red[threadIdx.x] = (i < NBINS) ? counts[i] : 0;
  __syncthreads();
  for (int s = 128; s > 0; s >>= 1) {
    if (threadIdx.x < s) red[threadIdx.x] += red[threadIdx.x + s];
    __syncthreads();
  }
  if (threadIdx.x == 0) bsum[blockIdx.x] = red[0];
}

__global__ void scan2_kernel(int* __restrict__ bsum, int NB) {  // exclusive, NB<=1024
  __shared__ int sh[1024];
  int t = threadIdx.x;
  int v = (t < NB) ? bsum[t] : 0;
  sh[t] = v;
  __syncthreads();
  for (int off = 1; off < 1024; off <<= 1) {
    int u = (t >= off) ? sh[t - off] : 0;
    __syncthreads();
    sh[t] += u;
    __syncthreads();
  }
  if (t < NB) bsum[t] = sh[t] - v;
}

__global__ void scan3_kernel(const int* __restrict__ counts, const int* __restrict__ bsum,
                             int* __restrict__ offs, int NBINS) {
  __shared__ int sh[256];
  int b = blockIdx.x, t = threadIdx.x;
  int i = b * 256 + t;
  int v = (i < NBINS) ? counts[i] : 0;
  sh[t] = v;
  __syncthreads();
  for (int off = 1; off < 256; off <<= 1) {
    int u = (t >= off) ? sh[t - off] : 0;
    __syncthreads();
    sh[t] += u;
    __syncthreads();
  }
  int excl = sh[t] - v + bsum[b];
  if (i < NBINS) offs[i] = excl;
  if (i == NBINS - 1) offs[NBINS] = excl + v;
}

__global__ void fill_kernel(const int* __restrict__ ei, const int* __restrict__ et,
                            const int* __restrict__ offs, int* __restrict__ cursor,
                            int* __restrict__ ev, int E, int M, int R, int RB) {
  for (int i = blockIdx.x * blockDim.x + threadIdx.x; i < E;
       i += gridDim.x * blockDim.x) {
    int dst = min(max(ei[E + i], 0), M - 1);
    int src = min(max(ei[i], 0), M - 1);
    int rel = min(max(et[i], 0), R - 1);
    int b = rel / RB;
    int bin = b * M + dst;
    int p = atomicAdd(&cursor[bin], 1);
    ev[offs[bin] + p] = src * RB + (rel - b * RB);
  }
}

// ---------------- gather: out[n] += sum over batch-CSR edges of xw[ev[s]] ----------------
template <int RELU>
__global__ void gather_kernel(const int* __restrict__ offs, const int* __restrict__ ev,
                              const unsigned short* __restrict__ xw,
                              float* __restrict__ out, int M, int base) {
  int w = blockIdx.x * (blockDim.x >> 6) + (threadIdx.x >> 6);
  int lane = threadIdx.x & 63;
  if (w >= M) return;
  int beg = offs[base + w], end = offs[base + w + 1];
  float a0 = 0, a1 = 0, a2 = 0, a3 = 0;
  int s = beg;
  for (; s + 3 < end; s += 4) {
    int v0 = ev[s], v1 = ev[s + 1], v2 = ev[s + 2], v3 = ev[s + 3];
    ushort4 t0 = *((const ushort4*)(xw + ((size_t)v0 << 8)) + lane);
    ushort4 t1 = *((const ushort4*)(xw + ((size_t)v1 << 8)) + lane);
    ushort4 t2 = *((const ushort4*)(xw + ((size_t)v2 << 8)) + lane);
    ushort4 t3 = *((const ushort4*)(xw + ((size_t)v3 << 8)) + lane);
    a0 += bf2f(t0.x) + bf2f(t1.x) + bf2f(t2.x) + bf2f(t3.x);
    a1 += bf2f(t0.y) + bf2f(t1.y) + bf2f(t2.y) + bf2f(t3.y);
    a2 += bf2f(t0.z) + bf2f(t1.z) + bf2f(t2.z) + bf2f(t3.z);
    a3 += bf2f(t0.w) + bf2f(t1.w) + bf2f(t2.w) + bf2f(t3.w);
  }
  for (; s < end; ++s) {
    int v = ev[s];
    ushort4 t = *((const ushort4*)(xw + ((size_t)v << 8)) + lane);
    a0 += bf2f(t.x); a1 += bf2f(t.y); a2 += bf2f(t.z); a3 += bf2f(t.w);
  }
  if (RELU || end > beg) {
    float4* o = (float4*)(out + (size_t)w * 256) + lane;
    float4 cur = *o;
    cur.x += a0; cur.y += a1; cur.z += a2; cur.w += a3;
    if (RELU) {
      cur.x = fmaxf(cur.x, 0.f); cur.y = fmaxf(cur.y, 0.f);
      cur.z = fmaxf(cur.z, 0.f); cur.w = fmaxf(cur.w, 0.f);
    }
    *o = cur;
  }
}

// ---------------- relu in place (fallback path only) ----------------
__global__ void relu_kernel(float* __restrict__ out, int n4) {
  int i = blockIdx.x * blockDim.x + threadIdx.x;
  if (i >= n4) return;
  float4 v = reinterpret_cast<float4*>(out)[i];
  v.x = fmaxf(v.x, 0.f); v.y = fmaxf(v.y, 0.f);
  v.z = fmaxf(v.z, 0.f); v.w = fmaxf(v.w, 0.f);
  reinterpret_cast<float4*>(out)[i] = v;
}

// ======== ws-free fallback tier (correctness only; used only if ws too small) ========
__global__ void fb_self_kernel(const float* __restrict__ x,
                               const float* __restrict__ Wself,
                               const float* __restrict__ bias,
                               float* __restrict__ out, int M) {
  int w = blockIdx.x * (blockDim.x >> 6) + (threadIdx.x >> 6);
  int lane = threadIdx.x & 63;
  int nw = gridDim.x * (blockDim.x >> 6);
  for (int n = w; n < M; n += nw) {
    float a0 = 0, a1 = 0, a2 = 0, a3 = 0;
    const float* xr = x + (size_t)n * 256;
    for (int d = 0; d < 256; ++d) {
      float xv = xr[d];
      float4 wv = *reinterpret_cast<const float4*>(Wself + (size_t)d * 256 + lane * 4);
      a0 = fmaf(xv, wv.x, a0); a1 = fmaf(xv, wv.y, a1);
      a2 = fmaf(xv, wv.z, a2); a3 = fmaf(xv, wv.w, a3);
    }
    float4 b = *reinterpret_cast<const float4*>(bias + lane * 4);
    float4 o = {a0 + b.x, a1 + b.y, a2 + b.z, a3 + b.w};
    *reinterpret_cast<float4*>(out + (size_t)n * 256 + lane * 4) = o;
  }
}

__global__ void fb_edge_kernel(const int* __restrict__ ei, const int* __restrict__ et,
                               const float* __restrict__ x,
                               const float* __restrict__ Wrel,
                               float* __restrict__ out, int E, int M, int R) {
  int w = blockIdx.x * (blockDim.x >> 6) + (threadIdx.x >> 6);
  int lane = threadIdx.x & 63;
  int nw = gridDim.x * (blockDim.x >> 6);
  for (int e = w; e < E; e += nw) {
    int src = min(max(ei[e], 0), M - 1);
    int dst = min(max(ei[E + e], 0), M - 1);
    int rel = min(max(et[e], 0), R - 1);
    const float* xr = x + (size_t)src * 256;
    const float* W = Wrel + (size_t)rel * 256 * 256;
    float a0 = 0, a1 = 0, a2 = 0, a3 = 0;
    for (int d = 0; d < 256; ++d) {
      float xv = xr[d];
      float4 wv = *reinterpret_cast<const float4*>(W + (size_t)d * 256 + lane * 4);
      a0 = fmaf(xv, wv.x, a0); a1 = fmaf(xv, wv.y, a1);
      a2 = fmaf(xv, wv.z, a2); a3 = fmaf(xv, wv.w, a3);
    }
    float* o = out + (size_t)dst * 256 + lane * 4;
    atomicAdd(o + 0, a0);
    atomicAdd(o + 1, a1);
    atomicAdd(o + 2, a2);
    atomicAdd(o + 3, a3);
  }
}

extern "C" void kernel_launch(void* const* d_in, const int* in_sizes, int n_in,
                              void* d_out, int out_size, void* d_ws, size_t ws_size,
                              hipStream_t stream) {
  const float* x = (const float*)d_in[0];
  const int* ei = (const int*)d_in[1];
  const int* et = (const int*)d_in[2];
  const float* Wrel = (const float*)d_in[3];
  const float* Wself = (const float*)d_in[4];
  const float* bias = (const float*)d_in[5];
  float* out = (float*)d_out;

  const int M = in_sizes[0] / D;        // nodes
  const int E = in_sizes[1] / 2;        // edges
  const int R = in_sizes[3] / (D * D);  // relations

  const int n4 = M * D / 4;

  // ---- ws plan: ints [counts nbM | cursor nbM | offs nbM+1 | bsum NB2 | ev E]
  //      then bf16 [Wt | xb? | xw(M*RB*D)]. Chosen from ws_size only (graph-safe).
  const size_t wtElems = (size_t)(R + 1) * D * D;
  const size_t xbElems = (size_t)M * D;
  const size_t yElems = (size_t)M * D;  // per relation

  int use_xb = 0, RB = 0, nb = 0;
  size_t nbM = 0, NB2 = 0;
  for (int pass = 0; pass < 2 && RB == 0; ++pass) {
    for (int rb = R; rb >= 1; rb >>= 1) {
      int nbc = (R + rb - 1) / rb;
      size_t nbm = (size_t)nbc * M;
      size_t nb2 = (nbm + 255) / 256;
      if (nb2 > 1024) continue;  // scan2 capacity
      size_t ib = (3 * nbm + 1 + nb2 + (size_t)E) * 4;
      if (ws_size < ib + 512) continue;
      size_t bfA = (ws_size - ib - 512) / 2;
      size_t need = wtElems + (pass == 0 ? xbElems : 0) + 512 + yElems * (size_t)rb;
      if (need <= bfA) {
        use_xb = (pass == 0); RB = rb; nb = nbc; nbM = nbm; NB2 = nb2;
        break;
      }
    }
  }

  if (RB == 0) {
    // ---- ws-free fallback: correct for ANY ws_size (never touches d_ws) ----
    fb_self_kernel<<<2048, 256, 0, stream>>>(x, Wself, bias, out, M);
    fb_edge_kernel<<<2048, 256, 0, stream>>>(ei, et, x, Wrel, out, E, M, R);
    relu_kernel<<<(n4 + 255) / 256, 256, 0, stream>>>(out, n4);
    return;
  }

  int* counts = (int*)d_ws;                 // nbM
  int* cursor = counts + nbM;               // nbM
  int* offs = cursor + nbM;                 // nbM+1
  int* bsum = offs + nbM + 1;               // NB2
  int* ev = bsum + NB2;                     // E
  uintptr_t bfp = (uintptr_t)(ev + E);
  bfp = (bfp + 255) & ~(uintptr_t)255;
  unsigned short* Wt = (unsigned short*)bfp;
  unsigned short* xb = Wt + wtElems;
  size_t off = wtElems + (use_xb ? xbElems : 0);
  off = (off + 255) & ~(size_t)255;
  unsigned short* xw = Wt + off;
  unsigned short* WtSelf = Wt + (size_t)R * D * D;

  // ---- CSR build (per batch,dst bins) ----
  hipMemsetAsync(counts, 0, 2 * nbM * 4, stream);  // counts + cursor
  hist_kernel<<<1024, 256, 0, stream>>>(ei, et, counts, E, M, R, RB);
  scan1_kernel<<<(int)NB2, 256, 0, stream>>>(counts, bsum, (int)nbM);
  scan2_kernel<<<1, 1024, 0, stream>>>(bsum, (int)NB2);
  scan3_kernel<<<(int)NB2, 256, 0, stream>>>(counts, bsum, offs, (int)nbM);
  fill_kernel<<<1024, 256, 0, stream>>>(ei, et, offs, cursor, ev, E, M, R, RB);

  // ---- dense path ----
  transpose_w_kernel<<<dim3(4, 4, R + 1), 256, 0, stream>>>(Wrel, Wself, Wt, R);
  if (use_xb)
    convert_x_kernel<<<(n4 + 255) / 256, 256, 0, stream>>>(x, xb, n4);

  const int MBt = (M + 255) / 256;
  for (int b = 0; b < nb; ++b) {
    int rlo = b * RB;
    int rbw = min(RB, R - rlo);
    int nxw = rbw * 2;                 // 128-col tiles of this batch's xw
    int nself = (b == 0) ? 2 : 0;      // fused self-transform tiles (256 cols)
    int ntiles = nxw + nself;
    const unsigned short* BtB = Wt + (size_t)rlo * D * D;
    if (use_xb)
      gemm_kernel<1><<<MBt * ntiles, 512, 0, stream>>>(
          xb, nullptr, BtB, WtSelf, xw, out, bias, M, rbw * 256, ntiles, nxw);
    else
      gemm_kernel<0><<<MBt * ntiles, 512, 0, stream>>>(
          nullptr, x, BtB, WtSelf, xw, out, bias, M, rbw * 256, ntiles, nxw);
    if (b == nb - 1)
      gather_kernel<1><<<(M + 3) / 4, 256, 0, stream>>>(offs, ev, xw, out, M, b * M);
    else
      gather_kernel<0><<<(M + 3) / 4, 256, 0, stream>>>(offs, ev, xw, out, M, b * M);
  }
}